// Round 6
// baseline (500.105 us; speedup 1.0000x reference)
//
#include <hip/hip_runtime.h>

// Round-6: bucket-sort points by 16^3-voxel cell before the fused
// MLP+trilinear kernel. Rounds 4/5 showed dur == FETCH_SIZE / ~3.2 TB/s
// (random 64B-line fetch ceiling; L2 hit ~0 on 64MB vol). Sorting makes each
// block's gather footprint (~37KB) L1/L2-resident: FETCH ~570 -> ~200 MB.
// Pipeline: memset hist -> hist_k -> scan_k (1 block) -> scat_k -> main.
// Main kernel reads sorted points, writes out[perm[i]]. XCD swizzle keeps
// consecutive sorted blocks on one XCD's L2. Per-point math is byte-identical
// to round 5 (absmax 5.9e-2 known-passing). Fallback to unsorted if ws small.

#define NPTS (64 * 32 * 32 * 32)   // 2,097,152
#define NBLK (NPTS / 256)          // 8192
#define NBUCK 4096                 // 16^3 cells of 16^3 voxels
#define SSTR 40   // shorts per LDS activation row (80 B)

typedef __attribute__((ext_vector_type(8))) short bf16x8;
typedef __attribute__((ext_vector_type(4))) short s16x4;
typedef __attribute__((ext_vector_type(4))) float f32x4;

__device__ __forceinline__ short bf16rne(float f) {
    unsigned u = __builtin_bit_cast(unsigned, f);
    return (short)((u + 0x7fffu + ((u >> 16) & 1u)) >> 16);
}
__device__ __forceinline__ float bf16tof(short s) {
    return __builtin_bit_cast(float, ((unsigned)(unsigned short)s) << 16);
}

__device__ __forceinline__ int bucket_of(float cx, float cy, float cz) {
    int bx = ((int)cx) >> 4, by = ((int)cy) >> 4, bz = ((int)cz) >> 4;
    bx = min(max(bx, 0), 15); by = min(max(by, 0), 15); bz = min(max(bz, 0), 15);
    return (bx << 8) | (by << 4) | bz;
}

__global__ __launch_bounds__(256)
void hist_k(const float4* __restrict__ x, int* __restrict__ hist) {
    int p = blockIdx.x * 256 + threadIdx.x;
    float4 v = x[p];
    atomicAdd(&hist[bucket_of(v.x, v.y, v.z)], 1);
}

__global__ __launch_bounds__(256)
void scan_k(int* __restrict__ hist) {   // exclusive scan over 4096 bins
    __shared__ int part[256];
    int t = threadIdx.x;
    int loc[16]; int s = 0;
    #pragma unroll
    for (int i = 0; i < 16; ++i) { loc[i] = hist[t * 16 + i]; s += loc[i]; }
    part[t] = s;
    __syncthreads();
    #pragma unroll
    for (int d = 1; d < 256; d <<= 1) {
        int v = (t >= d) ? part[t - d] : 0;
        __syncthreads();
        part[t] += v;
        __syncthreads();
    }
    int run = part[t] - s;   // exclusive prefix of this thread's 16-bin chunk
    #pragma unroll
    for (int i = 0; i < 16; ++i) { hist[t * 16 + i] = run; run += loc[i]; }
}

__global__ __launch_bounds__(256)
void scat_k(const float4* __restrict__ x, int* __restrict__ offs,
            float4* __restrict__ sx, int* __restrict__ perm) {
    int p = blockIdx.x * 256 + threadIdx.x;
    float4 v = x[p];
    int pos = atomicAdd(&offs[bucket_of(v.x, v.y, v.z)], 1);
    sx[pos] = v;
    perm[pos] = p;
}

__global__ __launch_bounds__(256, 8)
void deform_sample_mfma3(const float4* __restrict__ pts,  // sorted (or raw) points
                         const float4* __restrict__ W1,   // 3x32
                         const float4* __restrict__ b1,   // 32
                         const float*  __restrict__ W2,   // 32x32 [in][out]
                         const float*  __restrict__ b2,
                         const float*  __restrict__ W3,
                         const float*  __restrict__ b3,
                         const float*  __restrict__ Wf,   // 32x3
                         const float*  __restrict__ bf_,  // 3
                         const float*  __restrict__ vol,  // 256^3
                         float* __restrict__ out,
                         const int* __restrict__ perm)    // null -> identity
{
    __shared__ short lds[4 * 64 * SSTR];   // 20,480 B
    const int tid  = threadIdx.x;
    const int lane = tid & 63;
    const int wv   = tid >> 6;
    const int m16  = lane & 15;
    const int q    = lane >> 4;
    short* __restrict__ L = &lds[wv * 64 * SSTR];

    // XCD swizzle: consecutive sorted blocks -> same XCD's L2 (dispatch i%8).
    const int bid = (blockIdx.x & 7) * (NBLK / 8) + (blockIdx.x >> 3);
    const int i   = bid * 256 + tid;

    const float4 xv = pts[i];
    const float c0 = xv.x, c1 = xv.y, c2 = xv.z;

    // ---- layer 1 per-lane: h = cos(c@W1+b1), bf16 rows into LDS ----
    {
        bf16x8 hw;
        #pragma unroll
        for (int j4 = 0; j4 < 8; ++j4) {
            float4 wa = W1[j4], wb = W1[8 + j4], wc = W1[16 + j4], bb = b1[j4];
            float v0 = __cosf(fmaf(c0, wa.x, fmaf(c1, wb.x, fmaf(c2, wc.x, bb.x))));
            float v1 = __cosf(fmaf(c0, wa.y, fmaf(c1, wb.y, fmaf(c2, wc.y, bb.y))));
            float v2 = __cosf(fmaf(c0, wa.z, fmaf(c1, wb.z, fmaf(c2, wc.z, bb.z))));
            float v3 = __cosf(fmaf(c0, wa.w, fmaf(c1, wb.w, fmaf(c2, wc.w, bb.w))));
            int o = (j4 & 1) * 4;
            hw[o+0] = bf16rne(v0); hw[o+1] = bf16rne(v1);
            hw[o+2] = bf16rne(v2); hw[o+3] = bf16rne(v3);
            if (j4 & 1)
                *(bf16x8*)&L[lane * SSTR + (j4 - 1) * 4] = hw;
        }
    }
    __syncthreads();

    // ---- layers 2 and 3 via MFMA (A=weights, B=activations) ----
    const float* const Wly[2] = { W2, W3 };
    const float* const bly[2] = { b2, b3 };
    #pragma unroll
    for (int ly = 0; ly < 2; ++ly) {
        const float* __restrict__ W  = Wly[ly];
        const float* __restrict__ bb = bly[ly];
        bf16x8 A0, A1;
        #pragma unroll
        for (int j = 0; j < 8; ++j) {
            A0[j] = bf16rne(W[(q * 8 + j) * 32 + m16]);
            A1[j] = bf16rne(W[(q * 8 + j) * 32 + 16 + m16]);
        }
        const float4 blo = *(const float4*)&bb[q * 4];
        const float4 bhi = *(const float4*)&bb[16 + q * 4];

        #pragma unroll
        for (int t = 0; t < 4; ++t) {
            bf16x8 bfrag = *(const bf16x8*)&L[(t * 16 + m16) * SSTR + q * 8];
            f32x4 z = { 0.f, 0.f, 0.f, 0.f };
            f32x4 d0 = __builtin_amdgcn_mfma_f32_16x16x32_bf16(A0, bfrag, z, 0, 0, 0);
            f32x4 d1 = __builtin_amdgcn_mfma_f32_16x16x32_bf16(A1, bfrag, z, 0, 0, 0);

            s16x4 w0, w1;
            w0[0] = bf16rne(__cosf(d0[0] + blo.x));
            w0[1] = bf16rne(__cosf(d0[1] + blo.y));
            w0[2] = bf16rne(__cosf(d0[2] + blo.z));
            w0[3] = bf16rne(__cosf(d0[3] + blo.w));
            w1[0] = bf16rne(__cosf(d1[0] + bhi.x));
            w1[1] = bf16rne(__cosf(d1[1] + bhi.y));
            w1[2] = bf16rne(__cosf(d1[2] + bhi.z));
            w1[3] = bf16rne(__cosf(d1[3] + bhi.w));
            *(s16x4*)&L[(t * 16 + m16) * SSTR + q * 4]      = w0;
            *(s16x4*)&L[(t * 16 + m16) * SSTR + 16 + q * 4] = w1;
        }
        __syncthreads();
    }

    // ---- read own row; final c += 5*(h3@Wf + bf) ----
    float d0 = bf_[0], d1 = bf_[1], d2 = bf_[2];
    #pragma unroll
    for (int j4 = 0; j4 < 8; ++j4) {
        s16x4 v = *(const s16x4*)&L[lane * SSTR + j4 * 4];
        #pragma unroll
        for (int r = 0; r < 4; ++r) {
            float hv = bf16tof(v[r]);
            int ii = j4 * 4 + r;
            d0 = fmaf(hv, Wf[3*ii+0], d0);
            d1 = fmaf(hv, Wf[3*ii+1], d1);
            d2 = fmaf(hv, Wf[3*ii+2], d2);
        }
    }
    float e0 = fmaf(5.f, d0, c0);
    float e1 = fmaf(5.f, d1, c1);
    float e2 = fmaf(5.f, d2, c2);

    // ---- trilinear sample, vol (256,256,256,1) ----
    e0 = fminf(fmaxf(e0, 0.f), 255.f);
    e1 = fminf(fmaxf(e1, 0.f), 255.f);
    e2 = fminf(fmaxf(e2, 0.f), 255.f);
    float fl0 = floorf(e0), fl1 = floorf(e1), fl2 = floorf(e2);
    float fx = e0 - fl0, fy = e1 - fl1, fz = e2 - fl2;
    float gx = 1.f - fx, gy = 1.f - fy, gz = 1.f - fz;
    int x0 = (int)fl0, y0 = (int)fl1, z0 = (int)fl2;
    int x1 = min(x0 + 1, 255), y1 = min(y0 + 1, 255), z1 = min(z0 + 1, 255);
    int b00 = (x0 << 16) | (y0 << 8);
    int b01 = (x0 << 16) | (y1 << 8);
    int b10 = (x1 << 16) | (y0 << 8);
    int b11 = (x1 << 16) | (y1 << 8);
    float v000 = vol[b00 + z0], v001 = vol[b00 + z1];
    float v010 = vol[b01 + z0], v011 = vol[b01 + z1];
    float v100 = vol[b10 + z0], v101 = vol[b10 + z1];
    float v110 = vol[b11 + z0], v111 = vol[b11 + z1];

    float r = gz * (gy * (gx*v000 + fx*v100) + fy * (gx*v010 + fx*v110))
            + fz * (gy * (gx*v001 + fx*v101) + fy * (gx*v011 + fx*v111));

    out[perm ? perm[i] : i] = r;
}

extern "C" void kernel_launch(void* const* d_in, const int* in_sizes, int n_in,
                              void* d_out, int out_size, void* d_ws, size_t ws_size,
                              hipStream_t stream) {
    const float4* x   = (const float4*)d_in[0];
    const float4* W1  = (const float4*)d_in[1];
    const float4* b1  = (const float4*)d_in[2];
    const float*  W2  = (const float*)d_in[3];
    const float*  b2  = (const float*)d_in[4];
    const float*  W3  = (const float*)d_in[5];
    const float*  b3  = (const float*)d_in[6];
    const float*  Wf  = (const float*)d_in[7];
    const float*  bf_ = (const float*)d_in[8];
    const float*  vol = (const float*)d_in[9];
    float* out = (float*)d_out;

    char* ws = (char*)d_ws;
    int*    hist = (int*)ws;                                     // 16 KB @ 0
    float4* sx   = (float4*)(ws + 65536);                        // 32 MB
    int*    perm = (int*)(ws + 65536 + (size_t)NPTS * 16);       // 8 MB
    size_t  need = 65536 + (size_t)NPTS * 16 + (size_t)NPTS * 4;

    if (ws_size >= need) {
        hipMemsetAsync(hist, 0, NBUCK * sizeof(int), stream);
        hist_k<<<NBLK, 256, 0, stream>>>(x, hist);
        scan_k<<<1, 256, 0, stream>>>(hist);
        scat_k<<<NBLK, 256, 0, stream>>>(x, hist, sx, perm);
        deform_sample_mfma3<<<NBLK, 256, 0, stream>>>(sx, W1, b1, W2, b2, W3, b3,
                                                      Wf, bf_, vol, out, perm);
    } else {
        deform_sample_mfma3<<<NBLK, 256, 0, stream>>>(x, W1, b1, W2, b2, W3, b3,
                                                      Wf, bf_, vol, out, nullptr);
    }
}

// Round 7
// 212.213 us; speedup vs baseline: 2.3566x; 2.3566x over previous
//
#include <hip/hip_runtime.h>

// Round-7: brick-retiled fp16 volume instead of sorting.
// R4/R5 showed dur == FETCH/3.2TB/s (random 64B-line gather ceiling). R6's
// sort fixed main (~95us) but cost 300us in contended global atomics.
// Here: retile vol once per launch into d_ws as fp16 with one 64B line =
// 4x2x4 (x,y,z) voxel brick: byte addr = x[7:2]y[7:1]z[7:2]x[1:0]y[0]z[1:0]*2.
// Lines/point: 1.25*1.5*1.25 = 2.34 (vs 4.25); z-pair = one aligned u64 load
// (+25% predicated second) -> ~5 req/pt (vs 16.8). MLP identical to round 5.
// Fallback: direct f32 gather (round-5 proven) if ws_size < 32MB.

#define NPTS (64 * 32 * 32 * 32)
#define NBLK (NPTS / 256)
#define SSTR 40   // shorts per LDS activation row (80 B)

typedef __attribute__((ext_vector_type(8))) short bf16x8;
typedef __attribute__((ext_vector_type(4))) short s16x4;
typedef __attribute__((ext_vector_type(4))) float f32x4;
typedef unsigned long long u64;
typedef unsigned short u16;

__device__ __forceinline__ short bf16rne(float f) {
    unsigned u = __builtin_bit_cast(unsigned, f);
    return (short)((u + 0x7fffu + ((u >> 16) & 1u)) >> 16);
}
__device__ __forceinline__ float bf16tof(short s) {
    return __builtin_bit_cast(float, ((unsigned)(unsigned short)s) << 16);
}
__device__ __forceinline__ float h2f(u16 h) {
    return (float)__builtin_bit_cast(_Float16, h);
}
__device__ __forceinline__ u16 f2h(float f) {
    return __builtin_bit_cast(u16, (_Float16)f);
}

// ---- retile: vol (256^3 f32, z fastest) -> fp16 bricks in d_ws ----
// Thread t writes dst u64 t: q = t&7 (=lx*2+ly), gz = (t>>3)&63,
// gy = (t>>9)&127, gx = t>>16... (gyx = t>>9: gy = gyx&127, gx = gyx>>7).
// Reads float4 vol[x][y][4gz..4gz+3] (128B runs per q-row). Writes coalesced.
__global__ __launch_bounds__(256)
void retile_k(const float4* __restrict__ vol, u64* __restrict__ dst) {
    int t   = blockIdx.x * 256 + threadIdx.x;   // 0..4,194,303
    int q   = t & 7;
    int gz  = (t >> 3) & 63;
    int gyx = t >> 9;
    int x = ((gyx >> 7) << 2) + (q >> 1);
    int y = ((gyx & 127) << 1) + (q & 1);
    float4 v = vol[(((x << 8) + y) << 6) + gz];
    u64 r =  (u64)f2h(v.x)
          | ((u64)f2h(v.y) << 16)
          | ((u64)f2h(v.z) << 32)
          | ((u64)f2h(v.w) << 48);
    dst[t] = r;
}

template <int BRICK>
__global__ __launch_bounds__(256, 8)
void deform_sample_k(const float4* __restrict__ x,    // (N,4)
                     const float4* __restrict__ W1,   // 3x32
                     const float4* __restrict__ b1,   // 32
                     const float*  __restrict__ W2,   // 32x32 [in][out]
                     const float*  __restrict__ b2,
                     const float*  __restrict__ W3,
                     const float*  __restrict__ b3,
                     const float*  __restrict__ Wf,   // 32x3
                     const float*  __restrict__ bf_,  // 3
                     const float*  __restrict__ volf, // 256^3 f32 (fallback)
                     const u64*    __restrict__ volh, // fp16 bricks (BRICK)
                     float* __restrict__ out)
{
    __shared__ short lds[4 * 64 * SSTR];   // 20,480 B
    const int tid  = threadIdx.x;
    const int lane = tid & 63;
    const int wv   = tid >> 6;
    const int m16  = lane & 15;
    const int q    = lane >> 4;
    short* __restrict__ L = &lds[wv * 64 * SSTR];

    const int p = blockIdx.x * 256 + tid;   // grid exact: 8192 blocks

    const float4 xv = x[p];
    const float c0 = xv.x, c1 = xv.y, c2 = xv.z;

    // ---- layer 1 per-lane: h = cos(c@W1+b1), bf16 rows into LDS ----
    {
        bf16x8 hw;
        #pragma unroll
        for (int j4 = 0; j4 < 8; ++j4) {
            float4 wa = W1[j4], wb = W1[8 + j4], wc = W1[16 + j4], bb = b1[j4];
            float v0 = __cosf(fmaf(c0, wa.x, fmaf(c1, wb.x, fmaf(c2, wc.x, bb.x))));
            float v1 = __cosf(fmaf(c0, wa.y, fmaf(c1, wb.y, fmaf(c2, wc.y, bb.y))));
            float v2 = __cosf(fmaf(c0, wa.z, fmaf(c1, wb.z, fmaf(c2, wc.z, bb.z))));
            float v3 = __cosf(fmaf(c0, wa.w, fmaf(c1, wb.w, fmaf(c2, wc.w, bb.w))));
            int o = (j4 & 1) * 4;
            hw[o+0] = bf16rne(v0); hw[o+1] = bf16rne(v1);
            hw[o+2] = bf16rne(v2); hw[o+3] = bf16rne(v3);
            if (j4 & 1)
                *(bf16x8*)&L[lane * SSTR + (j4 - 1) * 4] = hw;
        }
    }
    __syncthreads();

    // ---- layers 2 and 3 via MFMA (A=weights, B=activations) ----
    const float* const Wly[2] = { W2, W3 };
    const float* const bly[2] = { b2, b3 };
    #pragma unroll
    for (int ly = 0; ly < 2; ++ly) {
        const float* __restrict__ W  = Wly[ly];
        const float* __restrict__ bb = bly[ly];
        bf16x8 A0, A1;
        #pragma unroll
        for (int j = 0; j < 8; ++j) {
            A0[j] = bf16rne(W[(q * 8 + j) * 32 + m16]);
            A1[j] = bf16rne(W[(q * 8 + j) * 32 + 16 + m16]);
        }
        const float4 blo = *(const float4*)&bb[q * 4];
        const float4 bhi = *(const float4*)&bb[16 + q * 4];

        #pragma unroll
        for (int t = 0; t < 4; ++t) {
            bf16x8 bfrag = *(const bf16x8*)&L[(t * 16 + m16) * SSTR + q * 8];
            f32x4 z = { 0.f, 0.f, 0.f, 0.f };
            f32x4 d0 = __builtin_amdgcn_mfma_f32_16x16x32_bf16(A0, bfrag, z, 0, 0, 0);
            f32x4 d1 = __builtin_amdgcn_mfma_f32_16x16x32_bf16(A1, bfrag, z, 0, 0, 0);

            s16x4 w0, w1;
            w0[0] = bf16rne(__cosf(d0[0] + blo.x));
            w0[1] = bf16rne(__cosf(d0[1] + blo.y));
            w0[2] = bf16rne(__cosf(d0[2] + blo.z));
            w0[3] = bf16rne(__cosf(d0[3] + blo.w));
            w1[0] = bf16rne(__cosf(d1[0] + bhi.x));
            w1[1] = bf16rne(__cosf(d1[1] + bhi.y));
            w1[2] = bf16rne(__cosf(d1[2] + bhi.z));
            w1[3] = bf16rne(__cosf(d1[3] + bhi.w));
            *(s16x4*)&L[(t * 16 + m16) * SSTR + q * 4]      = w0;
            *(s16x4*)&L[(t * 16 + m16) * SSTR + 16 + q * 4] = w1;
        }
        __syncthreads();
    }

    // ---- read own row; final c += 5*(h3@Wf + bf) ----
    float d0 = bf_[0], d1 = bf_[1], d2 = bf_[2];
    #pragma unroll
    for (int j4 = 0; j4 < 8; ++j4) {
        s16x4 v = *(const s16x4*)&L[lane * SSTR + j4 * 4];
        #pragma unroll
        for (int r = 0; r < 4; ++r) {
            float hv = bf16tof(v[r]);
            int ii = j4 * 4 + r;
            d0 = fmaf(hv, Wf[3*ii+0], d0);
            d1 = fmaf(hv, Wf[3*ii+1], d1);
            d2 = fmaf(hv, Wf[3*ii+2], d2);
        }
    }
    float e0 = fmaf(5.f, d0, c0);
    float e1 = fmaf(5.f, d1, c1);
    float e2 = fmaf(5.f, d2, c2);

    // ---- trilinear sample ----
    e0 = fminf(fmaxf(e0, 0.f), 255.f);
    e1 = fminf(fmaxf(e1, 0.f), 255.f);
    e2 = fminf(fmaxf(e2, 0.f), 255.f);
    float fl0 = floorf(e0), fl1 = floorf(e1), fl2 = floorf(e2);
    float fx = e0 - fl0, fy = e1 - fl1, fz = e2 - fl2;
    float gx = 1.f - fx, gy = 1.f - fy, gz = 1.f - fz;
    int x0 = (int)fl0, y0 = (int)fl1, z0 = (int)fl2;
    int x1 = min(x0 + 1, 255), y1 = min(y0 + 1, 255), z1 = min(z0 + 1, 255);

    float v000, v001, v010, v011, v100, v101, v110, v111;

    if constexpr (BRICK) {
        // byte addr = x[7:2]<<19 | y[7:1]<<12 | z[7:2]<<6 | x[1:0]<<4 | y[0]<<3
        const int lz  = z0 & 3;
        const int zp  = (z0 >> 2) << 6;
        const int xp0 = ((x0 >> 2) << 19) | ((x0 & 3) << 4);
        const int xp1 = ((x1 >> 2) << 19) | ((x1 & 3) << 4);
        const int yp0 = ((y0 >> 1) << 12) | ((y0 & 1) << 3);
        const int yp1 = ((y1 >> 1) << 12) | ((y1 & 1) << 3);
        const char* vb = (const char*)volh;
        const int a00 = xp0 | yp0 | zp, a10 = xp1 | yp0 | zp;
        const int a01 = xp0 | yp1 | zp, a11 = xp1 | yp1 | zp;
        u64 L00 = *(const u64*)(vb + a00);
        u64 L10 = *(const u64*)(vb + a10);
        u64 L01 = *(const u64*)(vb + a01);
        u64 L11 = *(const u64*)(vb + a11);
        u64 H00 = 0, H10 = 0, H01 = 0, H11 = 0;
        const bool crossz = (lz == 3) && (z0 < 255);
        if (crossz) {   // z-pair straddles line: next gz line is +64 B
            H00 = *(const u64*)(vb + a00 + 64);
            H10 = *(const u64*)(vb + a10 + 64);
            H01 = *(const u64*)(vb + a01 + 64);
            H11 = *(const u64*)(vb + a11 + 64);
        }
        const int sh = lz * 16;
        const bool in_line = (lz < 3);
        auto ext = [&](u64 lo, u64 hi, float& a, float& b) {
            u64 s = lo >> sh;
            a = h2f((u16)s);
            float b_in = h2f((u16)(s >> 16));
            float b_nx = h2f((u16)hi);
            b = in_line ? b_in : (crossz ? b_nx : a);
        };
        ext(L00, H00, v000, v001);
        ext(L10, H10, v100, v101);
        ext(L01, H01, v010, v011);
        ext(L11, H11, v110, v111);
    } else {
        int b00 = (x0 << 16) | (y0 << 8);
        int b01 = (x0 << 16) | (y1 << 8);
        int b10 = (x1 << 16) | (y0 << 8);
        int b11 = (x1 << 16) | (y1 << 8);
        v000 = volf[b00 + z0]; v001 = volf[b00 + z1];
        v010 = volf[b01 + z0]; v011 = volf[b01 + z1];
        v100 = volf[b10 + z0]; v101 = volf[b10 + z1];
        v110 = volf[b11 + z0]; v111 = volf[b11 + z1];
    }

    float r = gz * (gy * (gx*v000 + fx*v100) + fy * (gx*v010 + fx*v110))
            + fz * (gy * (gx*v001 + fx*v101) + fy * (gx*v011 + fx*v111));

    out[p] = r;
}

extern "C" void kernel_launch(void* const* d_in, const int* in_sizes, int n_in,
                              void* d_out, int out_size, void* d_ws, size_t ws_size,
                              hipStream_t stream) {
    const float4* x   = (const float4*)d_in[0];
    const float4* W1  = (const float4*)d_in[1];
    const float4* b1  = (const float4*)d_in[2];
    const float*  W2  = (const float*)d_in[3];
    const float*  b2  = (const float*)d_in[4];
    const float*  W3  = (const float*)d_in[5];
    const float*  b3  = (const float*)d_in[6];
    const float*  Wf  = (const float*)d_in[7];
    const float*  bf_ = (const float*)d_in[8];
    const float*  vol = (const float*)d_in[9];
    float* out = (float*)d_out;

    const size_t need = (size_t)4194304 * 8;   // 32 MB fp16 bricks
    if (ws_size >= need) {
        u64* volh = (u64*)d_ws;
        retile_k<<<16384, 256, 0, stream>>>((const float4*)vol, volh);
        deform_sample_k<1><<<NBLK, 256, 0, stream>>>(x, W1, b1, W2, b2, W3, b3,
                                                     Wf, bf_, nullptr, volh, out);
    } else {
        deform_sample_k<0><<<NBLK, 256, 0, stream>>>(x, W1, b1, W2, b2, W3, b3,
                                                     Wf, bf_, vol, nullptr, out);
    }
}